// Round 10
// baseline (1977.155 us; speedup 1.0000x reference)
//
#include <hip/hip_runtime.h>
#include <hip/hip_bf16.h>
#include <math.h>

#define V_N    100000
#define E_N    400000
#define NFEAT  74
#define NEFEAT 12
#define G_DIM  200
#define LDA    224          // padded leading dim for all bf16 node matrices
#define L_N    2
#define NG_N   4000
#define NROWB  391          // cdiv(V_N,256)
#define NROWP  392          // padded to multiple of 8
#define NSWZ   (NROWP / 8 * 56)   // swizzled 1-D grid = 2744

static inline int cdiv(int a, int b) { return (a + b - 1) / b; }

__device__ __forceinline__ float lrelu_f(float x) { return x > 0.f ? x : 0.01f * x; }
__device__ __forceinline__ float sigmoid_f(float x) { return 1.f / (1.f + expf(-x)); }
__device__ __forceinline__ float elu_f(float x) { return x > 0.f ? x : expm1f(x); }
__device__ __forceinline__ float bf2f(__hip_bfloat16 x) { return __bfloat162float(x); }
__device__ __forceinline__ float bfbits2f(short s) {
    return __uint_as_float(((unsigned)(unsigned short)s) << 16);
}

__device__ __forceinline__ short f2bf(float f) {
    __hip_bfloat16 b = __float2bfloat16(f);
    short s;
    __builtin_memcpy(&s, &b, 2);
    return s;
}

typedef short short8 __attribute__((ext_vector_type(8)));
typedef short short4v __attribute__((ext_vector_type(4)));
typedef float f32x4 __attribute__((ext_vector_type(4)));

#define MFMA16(a, b, c) __builtin_amdgcn_mfma_f32_16x16x32_bf16((a), (b), (c), 0, 0, 0)

// XCD-aware swizzle: 7 cb-blocks of one row-tile land on the same XCD (lin%8)
__device__ __forceinline__ void swz_decode(int lin, int& rowBlk, int& cb)
{
    int grp = lin / 56;
    int rem = lin % 56;
    cb = rem >> 3;
    rowBlk = grp * 8 + (rem & 7);
}

// ---------------------------------------------------------------------------
__global__ __launch_bounds__(256)
void fill_kernel(float* __restrict__ p, float v, int n)
{
    int i = blockIdx.x * blockDim.x + threadIdx.x;
    if (i < n) p[i] = v;
}

__global__ __launch_bounds__(256)
void fill_int_kernel(int* __restrict__ p, int v, int n)
{
    int i = blockIdx.x * blockDim.x + threadIdx.x;
    if (i < n) p[i] = v;
}

// zero only the pad columns (k in [200,224)) of the 4 contiguous node matrices
__global__ __launch_bounds__(256)
void pad_zero_kernel(short* __restrict__ base, size_t VP)
{
    int idx = blockIdx.x * blockDim.x + threadIdx.x;
    if (idx >= 4 * V_N) return;
    int mat = idx / V_N, row = idx % V_N;
    short* p = base + (size_t)mat * VP + (long)row * LDA + G_DIM;
    short8 z = {};
    *(short8*)(p) = z;
    *(short8*)(p + 8) = z;
    *(short8*)(p + 16) = z;
}

// ---------------------------------------------------------------------------
// Weight preps
// ---------------------------------------------------------------------------
__global__ __launch_bounds__(256)
void wprep_kernel(const float* __restrict__ W, short* __restrict__ Wp, int K, int Kpad)
{
    int idx = blockIdx.x * 256 + threadIdx.x;
    if (idx >= 256 * Kpad) return;
    int j = idx / Kpad, k = idx % Kpad;
    float v = (j < G_DIM && k < K) ? W[(long)k * G_DIM + j] : 0.f;
    Wp[idx] = f2bf(v);
}

__global__ __launch_bounds__(256)
void wprep_tiled_kernel(const float* __restrict__ W, short* __restrict__ Wp)
{
    int idx = blockIdx.x * 256 + threadIdx.x;
    if (idx >= 7 * 7 * 1024) return;
    int cb = idx / (7 * 1024);
    int r = idx % (7 * 1024);
    int st = r / 1024;
    int r2 = r % 1024;
    int cc = r2 / 32, kk = r2 % 32;
    int col = cb * 32 + cc, k = st * 32 + kk;
    float v = (col < G_DIM && k < G_DIM) ? W[(long)k * G_DIM + col] : 0.f;
    Wp[idx] = f2bf(v);
}

__global__ __launch_bounds__(256)
void gru_wprep_kernel(const float* __restrict__ Wih, const float* __restrict__ Whh,
                      short* __restrict__ Wp)
{
    int idx = blockIdx.x * 256 + threadIdx.x;
    if (idx >= 7 * 14 * 3072) return;
    int cb = idx / (14 * 3072);
    int r = idx % (14 * 3072);
    int st = r / 3072;
    int r2 = r % 3072;
    int g = r2 / 1024;
    int r3 = r2 % 1024;
    int cc = r3 / 32, kk = r3 % 32;
    int col = cb * 32 + cc;
    float v = 0.f;
    if (col < G_DIM) {
        if (st < 7) {
            int k = st * 32 + kk;
            if (k < G_DIM) v = Wih[(long)k * (3 * G_DIM) + g * G_DIM + col];
        } else {
            int k = (st - 7) * 32 + kk;
            if (k < G_DIM) v = Whh[(long)k * (3 * G_DIM) + g * G_DIM + col];
        }
    }
    Wp[idx] = f2bf(v);
}

// ---------------------------------------------------------------------------
// CSR build
// ---------------------------------------------------------------------------
__global__ __launch_bounds__(256)
void hist_kernel(const int* __restrict__ dst, int* __restrict__ deg)
{
    int e = blockIdx.x * blockDim.x + threadIdx.x;
    if (e >= E_N) return;
    atomicAdd(&deg[dst[e]], 1);
}

__global__ __launch_bounds__(256)
void scan1_kernel(const int* __restrict__ deg, int* __restrict__ rp, int* __restrict__ bsum)
{
    __shared__ int s[256];
    int tid = threadIdx.x;
    int v = blockIdx.x * 256 + tid;
    int x = (v < V_N) ? deg[v] : 0;
    s[tid] = x;
    __syncthreads();
    for (int off = 1; off < 256; off <<= 1) {
        int t = (tid >= off) ? s[tid - off] : 0;
        __syncthreads();
        s[tid] += t;
        __syncthreads();
    }
    if (v < V_N) rp[v] = s[tid] - x;
    if (tid == 255) bsum[blockIdx.x] = s[255];
}

__global__ void scan2_kernel(int* __restrict__ bsum, int* __restrict__ rp, int nb)
{
    if (threadIdx.x != 0 || blockIdx.x != 0) return;
    int acc = 0;
    for (int b = 0; b < nb; b++) { int t = bsum[b]; bsum[b] = acc; acc += t; }
    rp[V_N] = acc;
}

__global__ __launch_bounds__(256)
void scan3_kernel(int* __restrict__ rp, const int* __restrict__ bsum)
{
    int v = blockIdx.x * 256 + threadIdx.x;
    if (v < V_N) rp[v] += bsum[v >> 8];
}

__global__ __launch_bounds__(256)
void csr_fill_kernel(const int* __restrict__ dst, const int* __restrict__ rp,
                     int* __restrict__ cnt, int* __restrict__ perm)
{
    int e = blockIdx.x * blockDim.x + threadIdx.x;
    if (e >= E_N) return;
    int d = dst[e];
    int pos = rp[d] + atomicAdd(&cnt[d], 1);
    perm[pos] = e;
}

// ---------------------------------------------------------------------------
// Dual 64x64 MFMA GEMM for fp32-A (K=74 pad 96): hv AND P in one A pass
// ---------------------------------------------------------------------------
__global__ __launch_bounds__(256)
void gemm_f32a_dual_kernel(const float* __restrict__ Af32,
                           const short* __restrict__ Wp1, const float* __restrict__ b1,
                           const short* __restrict__ Wp2, const float* __restrict__ b2,
                           __hip_bfloat16* __restrict__ C1,
                           __hip_bfloat16* __restrict__ C2)
{
    __shared__ short As[64 * 40];
    __shared__ short Bs1[64 * 40];
    __shared__ short Bs2[64 * 40];
    const int tid = threadIdx.x;
    const int lane = tid & 63;
    const int w = tid >> 6;
    const int quad = lane >> 4;
    const int lm = lane & 15;
    const int rowBase = blockIdx.y * 64;
    const int j0 = blockIdx.x * 64;
    const int arow = tid >> 2;
    const int akc = (tid & 3) * 8;
    const int agrow = rowBase + arow;

    f32x4 acc1[4] = {}, acc2[4] = {};

    for (int k0 = 0; k0 < 96; k0 += 32) {
        short8 av = {};
        if (agrow < V_N) {
            int gk = k0 + akc;
            #pragma unroll
            for (int i = 0; i < 8; i++) {
                int kg = gk + i;
                av[i] = (kg < NFEAT) ? f2bf(Af32[(long)agrow * NFEAT + kg]) : (short)0;
            }
        }
        *(short8*)&As[arow * 40 + akc] = av;
        {
            int col = tid >> 2;
            *(short8*)&Bs1[col * 40 + akc] =
                *(const short8*)(Wp1 + (long)(j0 + col) * 96 + k0 + akc);
            *(short8*)&Bs2[col * 40 + akc] =
                *(const short8*)(Wp2 + (long)(j0 + col) * 96 + k0 + akc);
        }
        __syncthreads();
        short8 a = *(short8*)&As[(w * 16 + lm) * 40 + quad * 8];
        #pragma unroll
        for (int nt = 0; nt < 4; nt++) {
            short8 bb1 = *(short8*)&Bs1[(nt * 16 + lm) * 40 + quad * 8];
            short8 bb2 = *(short8*)&Bs2[(nt * 16 + lm) * 40 + quad * 8];
            acc1[nt] = MFMA16(a, bb1, acc1[nt]);
            acc2[nt] = MFMA16(a, bb2, acc2[nt]);
        }
        __syncthreads();
    }

    #pragma unroll
    for (int nt = 0; nt < 4; nt++) {
        int col = j0 + nt * 16 + lm;
        if (col >= G_DIM) continue;
        float bv1 = b1[col], bv2 = b2[col];
        #pragma unroll
        for (int r = 0; r < 4; r++) {
            int grow = rowBase + w * 16 + quad * 4 + r;
            if (grow >= V_N) continue;
            C1[(long)grow * LDA + col] = __float2bfloat16(lrelu_f(acc1[nt][r] + bv1));
            C2[(long)grow * LDA + col] = __float2bfloat16(acc2[nt][r] + bv2);
        }
    }
}

// ---------------------------------------------------------------------------
// 256x32 MFMA GEMM, barrier-free/LDS-free: A fragments loaded directly
// global->VGPR (each A row chunk is wave-private), B direct from tiled Wp.
// ---------------------------------------------------------------------------
template<int EPI>   // 1 = bias only, 3 = elu
__global__ __launch_bounds__(256)
void gemm_bf16a_kernel(const __hip_bfloat16* __restrict__ Abf,
                       const short* __restrict__ Wp,
                       const float* __restrict__ bias,
                       __hip_bfloat16* __restrict__ Cbf)
{
    int rowBlk, cb;
    swz_decode(blockIdx.x, rowBlk, cb);
    if (rowBlk >= NROWB) return;
    const int tid = threadIdx.x;
    const int lane = tid & 63;
    const int w = tid >> 6;
    const int quad = lane >> 4;
    const int lm = lane & 15;
    const int j0 = cb * 32;
    const int rowBase = rowBlk * 256;
    const int arow0 = rowBase + w * 64 + lm;

    const short* WpB = Wp + (long)cb * (7 * 1024);
    f32x4 acc[4][2] = {};

    #pragma unroll 2
    for (int st = 0; st < 7; st++) {
        int kl = st * 32;
        const short* bs = WpB + st * 1024;
        short8 b0 = *(const short8*)(bs + (0 * 16 + lm) * 32 + quad * 8);
        short8 b1 = *(const short8*)(bs + (1 * 16 + lm) * 32 + quad * 8);
        #pragma unroll
        for (int rt = 0; rt < 4; rt++) {
            int gr = arow0 + rt * 16;
            short8 a = {};
            if (gr < V_N)
                a = *(const short8*)((const short*)Abf + (long)gr * LDA + kl + quad * 8);
            acc[rt][0] = MFMA16(a, b0, acc[rt][0]);
            acc[rt][1] = MFMA16(a, b1, acc[rt][1]);
        }
    }

    #pragma unroll
    for (int nt = 0; nt < 2; nt++) {
        int col = j0 + nt * 16 + lm;
        if (col >= G_DIM) continue;
        float bv = bias[col];
        #pragma unroll
        for (int rt = 0; rt < 4; rt++) {
            #pragma unroll
            for (int r = 0; r < 4; r++) {
                int grow = rowBase + w * 64 + rt * 16 + quad * 4 + r;
                if (grow >= V_N) continue;
                float v = acc[rt][nt][r] + bv;
                if (EPI == 3) v = elu_f(v);
                Cbf[(long)grow * LDA + col] = __float2bfloat16(v);
            }
        }
    }
}

// ---------------------------------------------------------------------------
// Fused MFMA GRU, barrier-free/LDS-free (direct global A/B fragment loads)
// ---------------------------------------------------------------------------
__global__ __launch_bounds__(256)
void gru_mfma_kernel(const __hip_bfloat16* __restrict__ xc,
                     const __hip_bfloat16* __restrict__ h,
                     const short* __restrict__ Wp,
                     const float* __restrict__ bih, const float* __restrict__ bhh,
                     __hip_bfloat16* __restrict__ out)
{
    int rowBlk, cb;
    swz_decode(blockIdx.x, rowBlk, cb);
    if (rowBlk >= NROWB) return;
    const int tid = threadIdx.x;
    const int lane = tid & 63;
    const int w = tid >> 6;
    const int quad = lane >> 4;
    const int lm = lane & 15;
    const int j0 = cb * 32;
    const int rowBase = rowBlk * 256;
    const int arow0 = rowBase + w * 64 + lm;

    const short* WpB = Wp + (long)cb * (14 * 3072);

    f32x4 aR[4][2] = {}, aZ[4][2] = {}, aNl[4][2] = {}, aNh[4][2] = {};

    #pragma unroll 1
    for (int phase = 0; phase < 2; phase++) {
        const short* Aptr = (phase == 0) ? (const short*)xc : (const short*)h;
        f32x4 (*aN)[2] = (phase == 0) ? aNl : aNh;
        #pragma unroll 2
        for (int st7 = 0; st7 < 7; st7++) {
            int kl = st7 * 32;
            const short* bs = WpB + (phase * 7 + st7) * 3072;
            short8 br[2], bz[2], bn[2];
            #pragma unroll
            for (int nt = 0; nt < 2; nt++) {
                br[nt] = *(const short8*)(bs + (0 * 32 + nt * 16 + lm) * 32 + quad * 8);
                bz[nt] = *(const short8*)(bs + (1 * 32 + nt * 16 + lm) * 32 + quad * 8);
                bn[nt] = *(const short8*)(bs + (2 * 32 + nt * 16 + lm) * 32 + quad * 8);
            }
            #pragma unroll
            for (int rt = 0; rt < 4; rt++) {
                int gr = arow0 + rt * 16;
                short8 a = {};
                if (gr < V_N)
                    a = *(const short8*)(Aptr + (long)gr * LDA + kl + quad * 8);
                #pragma unroll
                for (int nt = 0; nt < 2; nt++) {
                    aR[rt][nt] = MFMA16(a, br[nt], aR[rt][nt]);
                    aZ[rt][nt] = MFMA16(a, bz[nt], aZ[rt][nt]);
                    aN[rt][nt] = MFMA16(a, bn[nt], aN[rt][nt]);
                }
            }
        }
    }

    #pragma unroll
    for (int nt = 0; nt < 2; nt++) {
        int col = j0 + nt * 16 + lm;
        if (col >= G_DIM) continue;
        float b_ir = bih[col], b_iz = bih[G_DIM + col], b_in = bih[2 * G_DIM + col];
        float b_hr = bhh[col], b_hz = bhh[G_DIM + col], b_hn = bhh[2 * G_DIM + col];
        #pragma unroll
        for (int rt = 0; rt < 4; rt++) {
            #pragma unroll
            for (int r = 0; r < 4; r++) {
                int grow = rowBase + w * 64 + rt * 16 + quad * 4 + r;
                if (grow >= V_N) continue;
                float sr = aR[rt][nt][r] + b_ir + b_hr;
                float sz = aZ[rt][nt][r] + b_iz + b_hz;
                float gin = aNl[rt][nt][r] + b_in;
                float ghn = aNh[rt][nt][r] + b_hn;
                float rr = sigmoid_f(sr);
                float zz = sigmoid_f(sz);
                float nn = tanhf(gin + rr * ghn);
                float hval = bf2f(h[(long)grow * LDA + col]);
                float o = (1.f - zz) * nn + zz * hval;
                out[(long)grow * LDA + col] = __float2bfloat16(o > 0.f ? o : 0.f);
            }
        }
    }
}

// ---------------------------------------------------------------------------
// Node dot(s): s1[v] = X[v]·wa (+ s2[v] = X[v]·wb). Wave per node, vectorized.
// ---------------------------------------------------------------------------
__global__ __launch_bounds__(256)
void node_dot2_kernel(const __hip_bfloat16* __restrict__ X,
                      const float* __restrict__ wa, const float* __restrict__ wb,
                      float* __restrict__ s1, float* __restrict__ s2)
{
    int w = threadIdx.x >> 6, lane = threadIdx.x & 63;
    int v = blockIdx.x * 4 + w;
    if (v >= V_N) return;
    int vlane = (lane < 50) ? lane : 0;
    short4v pv = *(const short4v*)((const short*)X + (long)v * LDA + vlane * 4);
    f32x4 wav = *(const f32x4*)(wa + vlane * 4);
    float a = 0.f, b = 0.f;
    #pragma unroll
    for (int u = 0; u < 4; u++) a += bfbits2f(pv[u]) * wav[u];
    if (wb) {
        f32x4 wbv = *(const f32x4*)(wb + vlane * 4);
        #pragma unroll
        for (int u = 0; u < 4; u++) b += bfbits2f(pv[u]) * wbv[u];
    }
    if (lane >= 50) { a = 0.f; b = 0.f; }
    for (int off = 32; off > 0; off >>= 1) {
        a += __shfl_down(a, off, 64);
        if (wb) b += __shfl_down(b, off, 64);
    }
    if (lane == 0) {
        s1[v] = a;
        if (wb) s2[v] = b;
    }
}

// ---------------------------------------------------------------------------
// Ctx logits (he1 on the fly, vectorized): 2 edges per wave, 8 per block.
// ---------------------------------------------------------------------------
__global__ __launch_bounds__(256)
void ctx_logits_kernel(const __hip_bfloat16* __restrict__ P,
                       const float* __restrict__ efeat,
                       const int* __restrict__ src, const int* __restrict__ dst,
                       const float* __restrict__ s1,
                       const float* __restrict__ pe1W,
                       const float* __restrict__ pe2W, const float* __restrict__ pe2b,
                       float* __restrict__ logits)
{
    __shared__ float Wef[NEFEAT * G_DIM];
    __shared__ float w2s[G_DIM];
    const int tid = threadIdx.x;
    for (int i = tid; i < NEFEAT * G_DIM; i += 256) {
        int j = i / G_DIM, k = i % G_DIM;
        Wef[i] = pe1W[(long)(NFEAT + j) * G_DIM + k];
    }
    for (int i = tid; i < G_DIM; i += 256) w2s[i] = pe2W[G_DIM + i];
    __syncthreads();
    const f32x4* Wef4 = (const f32x4*)Wef;
    const f32x4* w2s4 = (const f32x4*)w2s;
    const int w = tid >> 6, lane = tid & 63;
    const int vlane = (lane < 50) ? lane : 0;
    const int e0 = (blockIdx.x * 4 + w) * 2;
    #pragma unroll
    for (int u = 0; u < 2; u++) {
        int e = e0 + u;
        if (e >= E_N) break;
        int s = src[e];
        float efv = (lane < NEFEAT) ? efeat[(long)e * NEFEAT + lane] : 0.f;
        f32x4 q = {};
        #pragma unroll
        for (int j = 0; j < NEFEAT; j++) {
            float ej = __shfl(efv, j, 64);
            f32x4 wv = Wef4[j * 50 + vlane];
            q += ej * wv;
        }
        short4v pv = *(const short4v*)((const short*)P + (long)s * LDA + vlane * 4);
        f32x4 wv2 = w2s4[vlane];
        float acc = 0.f;
        #pragma unroll
        for (int c = 0; c < 4; c++)
            acc += lrelu_f(bfbits2f(pv[c]) + q[c]) * wv2[c];
        if (lane >= 50) acc = 0.f;
        for (int off = 32; off > 0; off >>= 1) acc += __shfl_down(acc, off, 64);
        if (lane == 0) logits[e] = lrelu_f(acc + s1[dst[e]] + pe2b[0]);
    }
}

// ---------------------------------------------------------------------------
// Ctx fused softmax+agg: online softmax; wave per node; vectorized gathers.
// ---------------------------------------------------------------------------
__global__ __launch_bounds__(256)
void ctx_fused_agg_kernel(const __hip_bfloat16* __restrict__ P,
                          const float* __restrict__ efeat,
                          const int* __restrict__ src,
                          const int* __restrict__ rp, const int* __restrict__ perm,
                          const float* __restrict__ logits,
                          const float* __restrict__ pe1W,
                          __hip_bfloat16* __restrict__ hbar)
{
    __shared__ float Wef[NEFEAT * G_DIM];
    const int tid = threadIdx.x;
    for (int i = tid; i < NEFEAT * G_DIM; i += 256) {
        int j = i / G_DIM, k = i % G_DIM;
        Wef[i] = pe1W[(long)(NFEAT + j) * G_DIM + k];
    }
    __syncthreads();
    const f32x4* Wef4 = (const f32x4*)Wef;
    const int w = tid >> 6, lane = tid & 63;
    const int vlane = (lane < 50) ? lane : 0;
    int v = blockIdx.x * 4 + w;
    if (v >= V_N) return;
    int b = rp[v], en = rp[v + 1];
    f32x4 a = {};
    float m = -INFINITY, s = 0.f;
    for (int cb0 = b; cb0 < en; cb0 += 64) {
        int i = cb0 + lane;
        int e = 0, sE = 0;
        float l = -INFINITY;
        if (i < en) { e = perm[i]; sE = src[e]; l = logits[e]; }
        float lmax = l;
        for (int off = 32; off > 0; off >>= 1) lmax = fmaxf(lmax, __shfl_xor(lmax, off, 64));
        float m_new = fmaxf(m, lmax);
        float scale = expf(m - m_new);
        s *= scale; a *= scale;
        float wgt = (i < en) ? expf(l - m_new) : 0.f;
        float wsum = wgt;
        for (int off = 32; off > 0; off >>= 1) wsum += __shfl_xor(wsum, off, 64);
        s += wsum;
        int cnt = min(64, en - cb0);
        for (int t = 0; t < cnt; t++) {
            int eT = __shfl(e, t, 64);
            int sT = __shfl(sE, t, 64);
            float wT = __shfl(wgt, t, 64);
            float efv = (lane < NEFEAT) ? efeat[(long)eT * NEFEAT + lane] : 0.f;
            f32x4 q = {};
            #pragma unroll
            for (int j = 0; j < NEFEAT; j++) {
                float ej = __shfl(efv, j, 64);
                f32x4 wv = Wef4[j * 50 + vlane];
                q += ej * wv;
            }
            short4v pv = *(const short4v*)((const short*)P + (long)sT * LDA + vlane * 4);
            #pragma unroll
            for (int u = 0; u < 4; u++)
                a[u] += wT * lrelu_f(bfbits2f(pv[u]) + q[u]);
        }
        m = m_new;
    }
    float inv = (s > 0.f) ? 1.f / s : 0.f;
    if (lane < 50) {
        short4v o;
        #pragma unroll
        for (int u = 0; u < 4; u++) o[u] = f2bf(a[u] * inv);
        *(short4v*)((short*)hbar + (long)v * LDA + lane * 4) = o;
    }
}

// ---------------------------------------------------------------------------
// GNN fused softmax+agg: c[v] = elu(softmax-weighted sum of hvp[src]).
// ---------------------------------------------------------------------------
__global__ __launch_bounds__(256)
void gnn_fused_agg_kernel(const __hip_bfloat16* __restrict__ X,
                          const int* __restrict__ src,
                          const int* __restrict__ rp, const int* __restrict__ perm,
                          const float* __restrict__ s1, const float* __restrict__ s2,
                          const float* __restrict__ bias,
                          __hip_bfloat16* __restrict__ out)
{
    const int tid = threadIdx.x;
    const int w = tid >> 6, lane = tid & 63;
    const int vlane = (lane < 50) ? lane : 0;
    int v = blockIdx.x * 4 + w;
    if (v >= V_N) return;
    int b = rp[v], en = rp[v + 1];
    float s1v = s1[v] + bias[0];
    f32x4 a = {};
    float m = -INFINITY, s = 0.f;
    for (int cb0 = b; cb0 < en; cb0 += 64) {
        int i = cb0 + lane;
        int sE = 0;
        float l = -INFINITY;
        if (i < en) { int e = perm[i]; sE = src[e]; l = lrelu_f(s1v + s2[sE]); }
        float lmax = l;
        for (int off = 32; off > 0; off >>= 1) lmax = fmaxf(lmax, __shfl_xor(lmax, off, 64));
        float m_new = fmaxf(m, lmax);
        float scale = expf(m - m_new);
        s *= scale; a *= scale;
        float wgt = (i < en) ? expf(l - m_new) : 0.f;
        float wsum = wgt;
        for (int off = 32; off > 0; off >>= 1) wsum += __shfl_xor(wsum, off, 64);
        s += wsum;
        int cnt = min(64, en - cb0);
        for (int t = 0; t < cnt; t++) {
            int sT = __shfl(sE, t, 64);
            float wT = __shfl(wgt, t, 64);
            short4v pv = *(const short4v*)((const short*)X + (long)sT * LDA + vlane * 4);
            #pragma unroll
            for (int u = 0; u < 4; u++)
                a[u] += wT * bfbits2f(pv[u]);
        }
        m = m_new;
    }
    float inv = (s > 0.f) ? 1.f / s : 0.f;
    if (lane < 50) {
        short4v o;
        #pragma unroll
        for (int u = 0; u < 4; u++) o[u] = f2bf(elu_f(a[u] * inv));
        *(short4v*)((short*)out + (long)v * LDA + lane * 4) = o;
    }
}

// ---------------------------------------------------------------------------
// readout
// ---------------------------------------------------------------------------
__global__ __launch_bounds__(256)
void mask_kernel(const float* __restrict__ nfeat, float* __restrict__ mask)
{
    int v = blockIdx.x * blockDim.x + threadIdx.x;
    if (v >= V_N) return;
    const float* row = nfeat + (long)v * NFEAT;
    float s = row[NFEAT - 4] + row[NFEAT - 3] + row[NFEAT - 2] + row[NFEAT - 1];
    float m = s * (1.f - row[0]);
    mask[v] = 1.f / m - 1.f;
}

__global__ __launch_bounds__(256)
void readout_kernel(const __hip_bfloat16* __restrict__ nf, const float* __restrict__ predW,
                    const float* __restrict__ predb, const float* __restrict__ mask,
                    const int* __restrict__ gid, float* __restrict__ out_atom,
                    float* __restrict__ gsum)
{
    int gtid = blockIdx.x * blockDim.x + threadIdx.x;
    int v = gtid >> 6, lane = gtid & 63;
    if (v >= V_N) return;
    int vlane = (lane < 50) ? lane : 0;
    short4v pv = *(const short4v*)((const short*)nf + (long)v * LDA + vlane * 4);
    f32x4 wv = *(const f32x4*)(predW + vlane * 4);
    float acc = 0.f;
    #pragma unroll
    for (int u = 0; u < 4; u++) acc += bfbits2f(pv[u]) * wv[u];
    if (lane >= 50) acc = 0.f;
    for (int off = 32; off > 0; off >>= 1) acc += __shfl_down(acc, off, 64);
    if (lane == 0) {
        float p = acc + predb[0] + mask[v];
        out_atom[v] = p;
        atomicAdd(&gsum[gid[v]], exp10f(-p));
    }
}

__global__ __launch_bounds__(256)
void graph_out_kernel(const float* __restrict__ gsum, float* __restrict__ out_g)
{
    int g = blockIdx.x * blockDim.x + threadIdx.x;
    if (g >= NG_N) return;
    out_g[g] = -log10f(gsum[g]);
}

// ---------------------------------------------------------------------------
extern "C" void kernel_launch(void* const* d_in, const int* in_sizes, int n_in,
                              void* d_out, int out_size, void* d_ws, size_t ws_size,
                              hipStream_t stream)
{
    const float* node_feats = (const float*)d_in[0];
    const float* edge_feats = (const float*)d_in[1];
    const float* pn_W  = (const float*)d_in[2];
    const float* pn_b  = (const float*)d_in[3];
    const float* pe1_W = (const float*)d_in[4];
    const float* pe1_b = (const float*)d_in[5];
    const float* pe2_W = (const float*)d_in[6];
    const float* pe2_b = (const float*)d_in[7];
    const float* et_W  = (const float*)d_in[8];
    const float* et_b  = (const float*)d_in[9];
    const float* gru0_Wih = (const float*)d_in[10];
    const float* gru0_Whh = (const float*)d_in[11];
    const float* gru0_bih = (const float*)d_in[12];
    const float* gru0_bhh = (const float*)d_in[13];
    const float* gnn_pe_W = (const float*)d_in[14];
    const float* gnn_pe_b = (const float*)d_in[15];
    const float* gnn_pn_W = (const float*)d_in[16];
    const float* gnn_pn_b = (const float*)d_in[17];
    const float* gnn_gru_Wih = (const float*)d_in[18];
    const float* gnn_gru_Whh = (const float*)d_in[19];
    const float* gnn_gru_bih = (const float*)d_in[20];
    const float* gnn_gru_bhh = (const float*)d_in[21];
    const float* pred_W = (const float*)d_in[22];
    const float* pred_b = (const float*)d_in[23];
    const int* src = (const int*)d_in[24];
    const int* dst = (const int*)d_in[25];
    const int* gid = (const int*)d_in[26];

    float* out_g = (float*)d_out;
    float* out_atom = out_g + NG_N;

    char* base = (char*)d_ws;
    size_t off = 0;
    auto take = [&](size_t bytes) -> void* {
        void* p = base + off;
        off += (bytes + 255) & ~(size_t)255;
        return p;
    };
    const size_t VP = (size_t)V_N * LDA;
    const size_t WPL = (size_t)7 * 14 * 3072;
    float* mask   = (float*)take((size_t)V_N * 4);
    float* logits = (float*)take((size_t)E_N * 4);
    float* s1     = (float*)take((size_t)V_N * 4);
    float* s2     = (float*)take((size_t)V_N * 4);
    float* gsum   = (float*)take((size_t)NG_N * 4);
    __hip_bfloat16* c    = (__hip_bfloat16*)take(VP * 2);
    __hip_bfloat16* hv   = (__hip_bfloat16*)take(VP * 2);
    __hip_bfloat16* nf_a = (__hip_bfloat16*)take(VP * 2);
    __hip_bfloat16* nf_b = (__hip_bfloat16*)take(VP * 2);
    short* WpGru = (short*)take(3 * WPL * 2);
    short* Wp_pn0 = (short*)take((size_t)256 * 96 * 2);
    short* Wp_pe1 = (short*)take((size_t)256 * 96 * 2);
    short* Wp_et  = (short*)take((size_t)7 * 7 * 1024 * 2);
    short* Wp_pn1 = (short*)take((size_t)7 * 7 * 1024 * 2);
    short* Wp_pn2 = (short*)take((size_t)7 * 7 * 1024 * 2);
    int* deg  = (int*)take((size_t)V_N * 4);
    int* cnt  = (int*)take((size_t)V_N * 4);
    int* rp   = (int*)take((size_t)(V_N + 1) * 4);
    int* perm = (int*)take((size_t)E_N * 4);
    int* bsum = (int*)take((size_t)512 * 4);
    __hip_bfloat16* P    = nf_a;  // alias: nf_a written only at GRU0
    __hip_bfloat16* hbar = nf_b;  // alias: nf_b first written as layer-0 GRU output
    __hip_bfloat16* hvp  = hv;    // alias: hv dead after GRU0

    if (off > ws_size) {
        fill_kernel<<<cdiv(out_size, 256), 256, 0, stream>>>((float*)d_out, -12345.f, out_size);
        return;
    }

    const int BLK = 256;
    const int nScanBlocks = cdiv(V_N, 256);
    const dim3 gOld(4, cdiv(V_N, 64));
    const int gAgg = cdiv(V_N, 4);

    // zero only the pad columns of the 4 contiguous node matrices
    pad_zero_kernel<<<cdiv(4 * V_N, BLK), BLK, 0, stream>>>((short*)c, VP);

    // ---- weight prep ----
    gru_wprep_kernel<<<cdiv(7 * 14 * 3072, 256), BLK, 0, stream>>>(gru0_Wih, gru0_Whh, WpGru);
    for (int l = 0; l < L_N; l++)
        gru_wprep_kernel<<<cdiv(7 * 14 * 3072, 256), BLK, 0, stream>>>(
            gnn_gru_Wih + (size_t)l * G_DIM * 3 * G_DIM,
            gnn_gru_Whh + (size_t)l * G_DIM * 3 * G_DIM,
            WpGru + (size_t)(l + 1) * WPL);
    wprep_kernel<<<cdiv(256 * 96, 256), BLK, 0, stream>>>(pn_W, Wp_pn0, NFEAT, 96);
    wprep_kernel<<<cdiv(256 * 96, 256), BLK, 0, stream>>>(pe1_W, Wp_pe1, NFEAT, 96);
    wprep_tiled_kernel<<<cdiv(7 * 7 * 1024, 256), BLK, 0, stream>>>(et_W, Wp_et);
    wprep_tiled_kernel<<<cdiv(7 * 7 * 1024, 256), BLK, 0, stream>>>(gnn_pn_W, Wp_pn1);
    wprep_tiled_kernel<<<cdiv(7 * 7 * 1024, 256), BLK, 0, stream>>>(
        gnn_pn_W + (size_t)G_DIM * G_DIM, Wp_pn2);

    mask_kernel<<<cdiv(V_N, BLK), BLK, 0, stream>>>(node_feats, mask);

    // ---- CSR build (by dst) ----
    fill_int_kernel<<<cdiv(V_N, BLK), BLK, 0, stream>>>(deg, 0, V_N);
    hist_kernel<<<cdiv(E_N, BLK), BLK, 0, stream>>>(dst, deg);
    scan1_kernel<<<nScanBlocks, BLK, 0, stream>>>(deg, rp, bsum);
    scan2_kernel<<<1, 1, 0, stream>>>(bsum, rp, nScanBlocks);
    scan3_kernel<<<nScanBlocks, BLK, 0, stream>>>(rp, bsum);
    fill_int_kernel<<<cdiv(V_N, BLK), BLK, 0, stream>>>(cnt, 0, V_N);
    csr_fill_kernel<<<cdiv(E_N, BLK), BLK, 0, stream>>>(dst, rp, cnt, perm);

    // ---- GetContext ----
    gemm_f32a_dual_kernel<<<gOld, BLK, 0, stream>>>(
        node_feats, Wp_pn0, pn_b, Wp_pe1, pe1_b, hv, P);
    node_dot2_kernel<<<gAgg, BLK, 0, stream>>>(hv, pe2_W, nullptr, s1, nullptr);
    ctx_logits_kernel<<<cdiv(E_N, 8), BLK, 0, stream>>>(
        P, edge_feats, src, dst, s1, pe1_W, pe2_W, pe2_b, logits);
    ctx_fused_agg_kernel<<<gAgg, BLK, 0, stream>>>(
        P, edge_feats, src, rp, perm, logits, pe1_W, hbar);
    gemm_bf16a_kernel<3><<<NSWZ, BLK, 0, stream>>>(hbar, Wp_et, et_b, c);
    gru_mfma_kernel<<<NSWZ, BLK, 0, stream>>>(c, hv, WpGru, gru0_bih, gru0_bhh, nf_a);

    // ---- GNN layers ----
    __hip_bfloat16* cur = nf_a;
    __hip_bfloat16* nxt = nf_b;
    for (int l = 0; l < L_N; l++) {
        const float* pe_W = gnn_pe_W + (size_t)l * 2 * G_DIM;
        const float* pe_b = gnn_pe_b + l;
        const float* pnB  = gnn_pn_b + (size_t)l * G_DIM;
        const float* bih  = gnn_gru_bih + (size_t)l * 3 * G_DIM;
        const float* bhh  = gnn_gru_bhh + (size_t)l * 3 * G_DIM;
        const short* WpPn = (l == 0) ? Wp_pn1 : Wp_pn2;

        node_dot2_kernel<<<gAgg, BLK, 0, stream>>>(cur, pe_W, pe_W + G_DIM, s1, s2);
        gemm_bf16a_kernel<1><<<NSWZ, BLK, 0, stream>>>(cur, WpPn, pnB, hvp);
        gnn_fused_agg_kernel<<<gAgg, BLK, 0, stream>>>(
            hvp, src, rp, perm, s1, s2, pe_b, c);
        gru_mfma_kernel<<<NSWZ, BLK, 0, stream>>>(
            c, cur, WpGru + (size_t)(l + 1) * WPL, bih, bhh, nxt);

        __hip_bfloat16* tmp = cur; cur = nxt; nxt = tmp;
    }

    // ---- readout ----
    fill_kernel<<<cdiv(NG_N, BLK), BLK, 0, stream>>>(gsum, 0.f, NG_N);
    readout_kernel<<<cdiv(V_N * 64, BLK), BLK, 0, stream>>>(
        cur, pred_W, pred_b, mask, gid, out_atom, gsum);
    graph_out_kernel<<<cdiv(NG_N, BLK), BLK, 0, stream>>>(gsum, out_g);
}

// Round 11
// 1662.973 us; speedup vs baseline: 1.1889x; 1.1889x over previous
//
#include <hip/hip_runtime.h>
#include <hip/hip_bf16.h>
#include <math.h>

#define V_N    100000
#define E_N    400000
#define NFEAT  74
#define NEFEAT 12
#define G_DIM  200
#define LDA    224          // padded leading dim for all bf16 node matrices
#define L_N    2
#define NG_N   4000
#define NROWB  391          // cdiv(V_N,256)
#define NROWP  392          // padded to multiple of 8
#define NSWZ   (NROWP / 8 * 56)    // 7-cb swizzled grid = 2744 (gemm)
#define NSWZG  (NROWP / 8 * 112)   // 14-cb swizzled grid = 5488 (gru)

static inline int cdiv(int a, int b) { return (a + b - 1) / b; }

__device__ __forceinline__ float lrelu_f(float x) { return x > 0.f ? x : 0.01f * x; }
__device__ __forceinline__ float sigmoid_f(float x) { return 1.f / (1.f + expf(-x)); }
__device__ __forceinline__ float elu_f(float x) { return x > 0.f ? x : expm1f(x); }
__device__ __forceinline__ float bf2f(__hip_bfloat16 x) { return __bfloat162float(x); }
__device__ __forceinline__ float bfbits2f(short s) {
    return __uint_as_float(((unsigned)(unsigned short)s) << 16);
}

__device__ __forceinline__ short f2bf(float f) {
    __hip_bfloat16 b = __float2bfloat16(f);
    short s;
    __builtin_memcpy(&s, &b, 2);
    return s;
}

typedef short short8 __attribute__((ext_vector_type(8)));
typedef short short4v __attribute__((ext_vector_type(4)));
typedef float f32x4 __attribute__((ext_vector_type(4)));

#define MFMA16(a, b, c) __builtin_amdgcn_mfma_f32_16x16x32_bf16((a), (b), (c), 0, 0, 0)

// XCD-aware swizzles: all cb-blocks of one row-tile land on the same XCD (lin%8)
__device__ __forceinline__ void swz_decode7(int lin, int& rowBlk, int& cb)
{
    int grp = lin / 56;
    int rem = lin % 56;
    cb = rem >> 3;            // 0..6
    rowBlk = grp * 8 + (rem & 7);
}

__device__ __forceinline__ void swz_decode14(int lin, int& rowBlk, int& cb)
{
    int grp = lin / 112;
    int rem = lin % 112;
    cb = rem >> 3;            // 0..13
    rowBlk = grp * 8 + (rem & 7);
}

// ---------------------------------------------------------------------------
__global__ __launch_bounds__(256)
void fill_kernel(float* __restrict__ p, float v, int n)
{
    int i = blockIdx.x * blockDim.x + threadIdx.x;
    if (i < n) p[i] = v;
}

__global__ __launch_bounds__(256)
void fill_int_kernel(int* __restrict__ p, int v, int n)
{
    int i = blockIdx.x * blockDim.x + threadIdx.x;
    if (i < n) p[i] = v;
}

// zero only the pad columns (k in [200,224)) of the 4 contiguous node matrices
__global__ __launch_bounds__(256)
void pad_zero_kernel(short* __restrict__ base, size_t VP)
{
    int idx = blockIdx.x * blockDim.x + threadIdx.x;
    if (idx >= 4 * V_N) return;
    int mat = idx / V_N, row = idx % V_N;
    short* p = base + (size_t)mat * VP + (long)row * LDA + G_DIM;
    short8 z = {};
    *(short8*)(p) = z;
    *(short8*)(p + 8) = z;
    *(short8*)(p + 16) = z;
}

// ---------------------------------------------------------------------------
// Weight preps
// ---------------------------------------------------------------------------
__global__ __launch_bounds__(256)
void wprep_kernel(const float* __restrict__ W, short* __restrict__ Wp, int K, int Kpad)
{
    int idx = blockIdx.x * 256 + threadIdx.x;
    if (idx >= 256 * Kpad) return;
    int j = idx / Kpad, k = idx % Kpad;
    float v = (j < G_DIM && k < K) ? W[(long)k * G_DIM + j] : 0.f;
    Wp[idx] = f2bf(v);
}

// Tiled for K=224 GEMM: Wp[cb<7][st<7][cc<32][kk<32]
__global__ __launch_bounds__(256)
void wprep_tiled_kernel(const float* __restrict__ W, short* __restrict__ Wp)
{
    int idx = blockIdx.x * 256 + threadIdx.x;
    if (idx >= 7 * 7 * 1024) return;
    int cb = idx / (7 * 1024);
    int r = idx % (7 * 1024);
    int st = r / 1024;
    int r2 = r % 1024;
    int cc = r2 / 32, kk = r2 % 32;
    int col = cb * 32 + cc, k = st * 32 + kk;
    float v = (col < G_DIM && k < G_DIM) ? W[(long)k * G_DIM + col] : 0.f;
    Wp[idx] = f2bf(v);
}

// GRU tiled (16-col blocks): Wp[cb<14][st<14][g<3][cc<16][kk<32]
// st<7 -> Wih (k = st*32+kk), st>=7 -> Whh (k = (st-7)*32+kk)
__global__ __launch_bounds__(256)
void gru_wprep_kernel(const float* __restrict__ Wih, const float* __restrict__ Whh,
                      short* __restrict__ Wp)
{
    int idx = blockIdx.x * 256 + threadIdx.x;
    if (idx >= 14 * 14 * 1536) return;
    int cb = idx / (14 * 1536);
    int r = idx % (14 * 1536);
    int st = r / 1536;
    int r2 = r % 1536;
    int g = r2 / 512;
    int r3 = r2 % 512;
    int cc = r3 / 32, kk = r3 % 32;
    int col = cb * 16 + cc;
    float v = 0.f;
    if (col < G_DIM) {
        if (st < 7) {
            int k = st * 32 + kk;
            if (k < G_DIM) v = Wih[(long)k * (3 * G_DIM) + g * G_DIM + col];
        } else {
            int k = (st - 7) * 32 + kk;
            if (k < G_DIM) v = Whh[(long)k * (3 * G_DIM) + g * G_DIM + col];
        }
    }
    Wp[idx] = f2bf(v);
}

// ---------------------------------------------------------------------------
// CSR build
// ---------------------------------------------------------------------------
__global__ __launch_bounds__(256)
void hist_kernel(const int* __restrict__ dst, int* __restrict__ deg)
{
    int e = blockIdx.x * blockDim.x + threadIdx.x;
    if (e >= E_N) return;
    atomicAdd(&deg[dst[e]], 1);
}

__global__ __launch_bounds__(256)
void scan1_kernel(const int* __restrict__ deg, int* __restrict__ rp, int* __restrict__ bsum)
{
    __shared__ int s[256];
    int tid = threadIdx.x;
    int v = blockIdx.x * 256 + tid;
    int x = (v < V_N) ? deg[v] : 0;
    s[tid] = x;
    __syncthreads();
    for (int off = 1; off < 256; off <<= 1) {
        int t = (tid >= off) ? s[tid - off] : 0;
        __syncthreads();
        s[tid] += t;
        __syncthreads();
    }
    if (v < V_N) rp[v] = s[tid] - x;
    if (tid == 255) bsum[blockIdx.x] = s[255];
}

__global__ void scan2_kernel(int* __restrict__ bsum, int* __restrict__ rp, int nb)
{
    if (threadIdx.x != 0 || blockIdx.x != 0) return;
    int acc = 0;
    for (int b = 0; b < nb; b++) { int t = bsum[b]; bsum[b] = acc; acc += t; }
    rp[V_N] = acc;
}

__global__ __launch_bounds__(256)
void scan3_kernel(int* __restrict__ rp, const int* __restrict__ bsum)
{
    int v = blockIdx.x * 256 + threadIdx.x;
    if (v < V_N) rp[v] += bsum[v >> 8];
}

__global__ __launch_bounds__(256)
void csr_fill_kernel(const int* __restrict__ dst, const int* __restrict__ rp,
                     int* __restrict__ cnt, int* __restrict__ perm)
{
    int e = blockIdx.x * blockDim.x + threadIdx.x;
    if (e >= E_N) return;
    int d = dst[e];
    int pos = rp[d] + atomicAdd(&cnt[d], 1);
    perm[pos] = e;
}

// ---------------------------------------------------------------------------
// Dual 64x64 MFMA GEMM for fp32-A (K=74 pad 96): hv AND P in one A pass
// ---------------------------------------------------------------------------
__global__ __launch_bounds__(256)
void gemm_f32a_dual_kernel(const float* __restrict__ Af32,
                           const short* __restrict__ Wp1, const float* __restrict__ b1,
                           const short* __restrict__ Wp2, const float* __restrict__ b2,
                           __hip_bfloat16* __restrict__ C1,
                           __hip_bfloat16* __restrict__ C2)
{
    __shared__ short As[64 * 40];
    __shared__ short Bs1[64 * 40];
    __shared__ short Bs2[64 * 40];
    const int tid = threadIdx.x;
    const int lane = tid & 63;
    const int w = tid >> 6;
    const int quad = lane >> 4;
    const int lm = lane & 15;
    const int rowBase = blockIdx.y * 64;
    const int j0 = blockIdx.x * 64;
    const int arow = tid >> 2;
    const int akc = (tid & 3) * 8;
    const int agrow = rowBase + arow;

    f32x4 acc1[4] = {}, acc2[4] = {};

    for (int k0 = 0; k0 < 96; k0 += 32) {
        short8 av = {};
        if (agrow < V_N) {
            int gk = k0 + akc;
            #pragma unroll
            for (int i = 0; i < 8; i++) {
                int kg = gk + i;
                av[i] = (kg < NFEAT) ? f2bf(Af32[(long)agrow * NFEAT + kg]) : (short)0;
            }
        }
        *(short8*)&As[arow * 40 + akc] = av;
        {
            int col = tid >> 2;
            *(short8*)&Bs1[col * 40 + akc] =
                *(const short8*)(Wp1 + (long)(j0 + col) * 96 + k0 + akc);
            *(short8*)&Bs2[col * 40 + akc] =
                *(const short8*)(Wp2 + (long)(j0 + col) * 96 + k0 + akc);
        }
        __syncthreads();
        short8 a = *(short8*)&As[(w * 16 + lm) * 40 + quad * 8];
        #pragma unroll
        for (int nt = 0; nt < 4; nt++) {
            short8 bb1 = *(short8*)&Bs1[(nt * 16 + lm) * 40 + quad * 8];
            short8 bb2 = *(short8*)&Bs2[(nt * 16 + lm) * 40 + quad * 8];
            acc1[nt] = MFMA16(a, bb1, acc1[nt]);
            acc2[nt] = MFMA16(a, bb2, acc2[nt]);
        }
        __syncthreads();
    }

    #pragma unroll
    for (int nt = 0; nt < 4; nt++) {
        int col = j0 + nt * 16 + lm;
        if (col >= G_DIM) continue;
        float bv1 = b1[col], bv2 = b2[col];
        #pragma unroll
        for (int r = 0; r < 4; r++) {
            int grow = rowBase + w * 16 + quad * 4 + r;
            if (grow >= V_N) continue;
            C1[(long)grow * LDA + col] = __float2bfloat16(lrelu_f(acc1[nt][r] + bv1));
            C2[(long)grow * LDA + col] = __float2bfloat16(acc2[nt][r] + bv2);
        }
    }
}

// ---------------------------------------------------------------------------
// 256x32 MFMA GEMM, bf16 A [V][LDA], K=224, Wp tiled; LDS-staged (r9 version)
// ---------------------------------------------------------------------------
template<int EPI>   // 1 = bias only, 3 = elu
__global__ __launch_bounds__(256)
void gemm_bf16a_kernel(const __hip_bfloat16* __restrict__ Abf,
                       const short* __restrict__ Wp,
                       const float* __restrict__ bias,
                       __hip_bfloat16* __restrict__ Cbf)
{
    __shared__ short As[256 * 32];
    __shared__ short Bs[32 * 32];
    int rowBlk, cb;
    swz_decode7(blockIdx.x, rowBlk, cb);
    if (rowBlk >= NROWB) return;
    const int tid = threadIdx.x;
    const int lane = tid & 63;
    const int w = tid >> 6;
    const int quad = lane >> 4;
    const int lm = lane & 15;
    const int j0 = cb * 32;
    const int rowBase = rowBlk * 256;
    const int sRow = tid >> 2;
    const int sChunk = (tid & 3) * 8;

    const short* WpB = Wp + (long)cb * (7 * 1024);
    f32x4 acc[4][2] = {};

    #pragma unroll 1
    for (int st = 0; st < 7; st++) {
        int kl = st * 32;
        #pragma unroll
        for (int p = 0; p < 4; p++) {
            int r = sRow + p * 64;
            int gr = rowBase + r;
            short8 v = {};
            if (gr < V_N) v = *(const short8*)((const short*)Abf + (long)gr * LDA + kl + sChunk);
            *(short8*)&As[r * 32 + sChunk] = v;
        }
        if (tid < 128)
            *(short8*)&Bs[tid * 8] = *(const short8*)(WpB + st * 1024 + tid * 8);
        __syncthreads();
        short8 b0 = *(short8*)&Bs[(0 * 16 + lm) * 32 + quad * 8];
        short8 b1 = *(short8*)&Bs[(1 * 16 + lm) * 32 + quad * 8];
        #pragma unroll
        for (int rt = 0; rt < 4; rt++) {
            short8 a = *(short8*)&As[(w * 64 + rt * 16 + lm) * 32 + quad * 8];
            acc[rt][0] = MFMA16(a, b0, acc[rt][0]);
            acc[rt][1] = MFMA16(a, b1, acc[rt][1]);
        }
        __syncthreads();
    }

    #pragma unroll
    for (int nt = 0; nt < 2; nt++) {
        int col = j0 + nt * 16 + lm;
        if (col >= G_DIM) continue;
        float bv = bias[col];
        #pragma unroll
        for (int rt = 0; rt < 4; rt++) {
            #pragma unroll
            for (int r = 0; r < 4; r++) {
                int grow = rowBase + w * 64 + rt * 16 + quad * 4 + r;
                if (grow >= V_N) continue;
                float v = acc[rt][nt][r] + bv;
                if (EPI == 3) v = elu_f(v);
                Cbf[(long)grow * LDA + col] = __float2bfloat16(v);
            }
        }
    }
}

// ---------------------------------------------------------------------------
// Fused MFMA GRU: 256 rows x 16 cols tile (14 cb blocks), LDS-staged.
// Accumulators: 16 f32x4 = 64 AGPR (half of r9). launch_bounds(256,3)
// forces total regs <= 170 -> 3 waves/SIMD.
// Wp layout [cb<14][st<14][g<3][cc<16][kk<32].
// ---------------------------------------------------------------------------
__global__ __launch_bounds__(256, 3)
void gru_mfma_kernel(const __hip_bfloat16* __restrict__ xc,
                     const __hip_bfloat16* __restrict__ h,
                     const short* __restrict__ Wp,
                     const float* __restrict__ bih, const float* __restrict__ bhh,
                     __hip_bfloat16* __restrict__ out)
{
    __shared__ short As[256 * 32];
    __shared__ short Bs[3 * 16 * 32];
    int rowBlk, cb;
    swz_decode14(blockIdx.x, rowBlk, cb);
    if (rowBlk >= NROWB) return;
    const int tid = threadIdx.x;
    const int lane = tid & 63;
    const int w = tid >> 6;
    const int quad = lane >> 4;
    const int lm = lane & 15;
    const int j0 = cb * 16;
    const int rowBase = rowBlk * 256;
    const int sRow = tid >> 2;
    const int sChunk = (tid & 3) * 8;

    const short* WpB = Wp + (long)cb * (14 * 1536);

    f32x4 aR[4] = {}, aZ[4] = {}, aNl[4] = {}, aNh[4] = {};

    #pragma unroll 1
    for (int st = 0; st < 14; st++) {
        const short* Aptr = (st < 7) ? (const short*)xc : (const short*)h;
        int kl = (st < 7 ? st : st - 7) * 32;
        #pragma unroll
        for (int p = 0; p < 4; p++) {
            int r = sRow + p * 64;
            int gr = rowBase + r;
            short8 v = {};
            if (gr < V_N) v = *(const short8*)(Aptr + (long)gr * LDA + kl + sChunk);
            *(short8*)&As[r * 32 + sChunk] = v;
        }
        if (tid < 192)
            *(short8*)&Bs[tid * 8] = *(const short8*)(WpB + st * 1536 + tid * 8);
        __syncthreads();
        short8 br = *(short8*)&Bs[(0 * 16 + lm) * 32 + quad * 8];
        short8 bz = *(short8*)&Bs[(1 * 16 + lm) * 32 + quad * 8];
        short8 bn = *(short8*)&Bs[(2 * 16 + lm) * 32 + quad * 8];
        #pragma unroll
        for (int rt = 0; rt < 4; rt++) {
            short8 a = *(short8*)&As[(w * 64 + rt * 16 + lm) * 32 + quad * 8];
            aR[rt] = MFMA16(a, br, aR[rt]);
            aZ[rt] = MFMA16(a, bz, aZ[rt]);
            if (st < 7) aNl[rt] = MFMA16(a, bn, aNl[rt]);
            else        aNh[rt] = MFMA16(a, bn, aNh[rt]);
        }
        __syncthreads();
    }

    int col = j0 + lm;
    if (col < G_DIM) {
        float b_ir = bih[col], b_iz = bih[G_DIM + col], b_in = bih[2 * G_DIM + col];
        float b_hr = bhh[col], b_hz = bhh[G_DIM + col], b_hn = bhh[2 * G_DIM + col];
        #pragma unroll
        for (int rt = 0; rt < 4; rt++) {
            #pragma unroll
            for (int r = 0; r < 4; r++) {
                int grow = rowBase + w * 64 + rt * 16 + quad * 4 + r;
                if (grow >= V_N) continue;
                float sr = aR[rt][r] + b_ir + b_hr;
                float sz = aZ[rt][r] + b_iz + b_hz;
                float gin = aNl[rt][r] + b_in;
                float ghn = aNh[rt][r] + b_hn;
                float rr = sigmoid_f(sr);
                float zz = sigmoid_f(sz);
                float nn = tanhf(gin + rr * ghn);
                float hval = bf2f(h[(long)grow * LDA + col]);
                float o = (1.f - zz) * nn + zz * hval;
                out[(long)grow * LDA + col] = __float2bfloat16(o > 0.f ? o : 0.f);
            }
        }
    }
}

// ---------------------------------------------------------------------------
// Node dot(s): s1[v] = X[v]·wa (+ s2[v] = X[v]·wb). Wave per node, vectorized.
// ---------------------------------------------------------------------------
__global__ __launch_bounds__(256)
void node_dot2_kernel(const __hip_bfloat16* __restrict__ X,
                      const float* __restrict__ wa, const float* __restrict__ wb,
                      float* __restrict__ s1, float* __restrict__ s2)
{
    int w = threadIdx.x >> 6, lane = threadIdx.x & 63;
    int v = blockIdx.x * 4 + w;
    if (v >= V_N) return;
    int vlane = (lane < 50) ? lane : 0;
    short4v pv = *(const short4v*)((const short*)X + (long)v * LDA + vlane * 4);
    f32x4 wav = *(const f32x4*)(wa + vlane * 4);
    float a = 0.f, b = 0.f;
    #pragma unroll
    for (int u = 0; u < 4; u++) a += bfbits2f(pv[u]) * wav[u];
    if (wb) {
        f32x4 wbv = *(const f32x4*)(wb + vlane * 4);
        #pragma unroll
        for (int u = 0; u < 4; u++) b += bfbits2f(pv[u]) * wbv[u];
    }
    if (lane >= 50) { a = 0.f; b = 0.f; }
    for (int off = 32; off > 0; off >>= 1) {
        a += __shfl_down(a, off, 64);
        if (wb) b += __shfl_down(b, off, 64);
    }
    if (lane == 0) {
        s1[v] = a;
        if (wb) s2[v] = b;
    }
}

// ---------------------------------------------------------------------------
// Ctx logits (he1 on the fly, vectorized): 2 edges per wave, 8 per block.
// ---------------------------------------------------------------------------
__global__ __launch_bounds__(256)
void ctx_logits_kernel(const __hip_bfloat16* __restrict__ P,
                       const float* __restrict__ efeat,
                       const int* __restrict__ src, const int* __restrict__ dst,
                       const float* __restrict__ s1,
                       const float* __restrict__ pe1W,
                       const float* __restrict__ pe2W, const float* __restrict__ pe2b,
                       float* __restrict__ logits)
{
    __shared__ float Wef[NEFEAT * G_DIM];
    __shared__ float w2s[G_DIM];
    const int tid = threadIdx.x;
    for (int i = tid; i < NEFEAT * G_DIM; i += 256) {
        int j = i / G_DIM, k = i % G_DIM;
        Wef[i] = pe1W[(long)(NFEAT + j) * G_DIM + k];
    }
    for (int i = tid; i < G_DIM; i += 256) w2s[i] = pe2W[G_DIM + i];
    __syncthreads();
    const f32x4* Wef4 = (const f32x4*)Wef;
    const f32x4* w2s4 = (const f32x4*)w2s;
    const int w = tid >> 6, lane = tid & 63;
    const int vlane = (lane < 50) ? lane : 0;
    const int e0 = (blockIdx.x * 4 + w) * 2;
    #pragma unroll
    for (int u = 0; u < 2; u++) {
        int e = e0 + u;
        if (e >= E_N) break;
        int s = src[e];
        float efv = (lane < NEFEAT) ? efeat[(long)e * NEFEAT + lane] : 0.f;
        f32x4 q = {};
        #pragma unroll
        for (int j = 0; j < NEFEAT; j++) {
            float ej = __shfl(efv, j, 64);
            f32x4 wv = Wef4[j * 50 + vlane];
            q += ej * wv;
        }
        short4v pv = *(const short4v*)((const short*)P + (long)s * LDA + vlane * 4);
        f32x4 wv2 = w2s4[vlane];
        float acc = 0.f;
        #pragma unroll
        for (int c = 0; c < 4; c++)
            acc += lrelu_f(bfbits2f(pv[c]) + q[c]) * wv2[c];
        if (lane >= 50) acc = 0.f;
        for (int off = 32; off > 0; off >>= 1) acc += __shfl_down(acc, off, 64);
        if (lane == 0) logits[e] = lrelu_f(acc + s1[dst[e]] + pe2b[0]);
    }
}

// ---------------------------------------------------------------------------
// Ctx fused softmax+agg: online softmax; wave per node; vectorized gathers.
// ---------------------------------------------------------------------------
__global__ __launch_bounds__(256)
void ctx_fused_agg_kernel(const __hip_bfloat16* __restrict__ P,
                          const float* __restrict__ efeat,
                          const int* __restrict__ src,
                          const int* __restrict__ rp, const int* __restrict__ perm,
                          const float* __restrict__ logits,
                          const float* __restrict__ pe1W,
                          __hip_bfloat16* __restrict__ hbar)
{
    __shared__ float Wef[NEFEAT * G_DIM];
    const int tid = threadIdx.x;
    for (int i = tid; i < NEFEAT * G_DIM; i += 256) {
        int j = i / G_DIM, k = i % G_DIM;
        Wef[i] = pe1W[(long)(NFEAT + j) * G_DIM + k];
    }
    __syncthreads();
    const f32x4* Wef4 = (const f32x4*)Wef;
    const int w = tid >> 6, lane = tid & 63;
    const int vlane = (lane < 50) ? lane : 0;
    int v = blockIdx.x * 4 + w;
    if (v >= V_N) return;
    int b = rp[v], en = rp[v + 1];
    f32x4 a = {};
    float m = -INFINITY, s = 0.f;
    for (int cb0 = b; cb0 < en; cb0 += 64) {
        int i = cb0 + lane;
        int e = 0, sE = 0;
        float l = -INFINITY;
        if (i < en) { e = perm[i]; sE = src[e]; l = logits[e]; }
        float lmax = l;
        for (int off = 32; off > 0; off >>= 1) lmax = fmaxf(lmax, __shfl_xor(lmax, off, 64));
        float m_new = fmaxf(m, lmax);
        float scale = expf(m - m_new);
        s *= scale; a *= scale;
        float wgt = (i < en) ? expf(l - m_new) : 0.f;
        float wsum = wgt;
        for (int off = 32; off > 0; off >>= 1) wsum += __shfl_xor(wsum, off, 64);
        s += wsum;
        int cnt = min(64, en - cb0);
        for (int t = 0; t < cnt; t++) {
            int eT = __shfl(e, t, 64);
            int sT = __shfl(sE, t, 64);
            float wT = __shfl(wgt, t, 64);
            float efv = (lane < NEFEAT) ? efeat[(long)eT * NEFEAT + lane] : 0.f;
            f32x4 q = {};
            #pragma unroll
            for (int j = 0; j < NEFEAT; j++) {
                float ej = __shfl(efv, j, 64);
                f32x4 wv = Wef4[j * 50 + vlane];
                q += ej * wv;
            }
            short4v pv = *(const short4v*)((const short*)P + (long)sT * LDA + vlane * 4);
            #pragma unroll
            for (int u = 0; u < 4; u++)
                a[u] += wT * lrelu_f(bfbits2f(pv[u]) + q[u]);
        }
        m = m_new;
    }
    float inv = (s > 0.f) ? 1.f / s : 0.f;
    if (lane < 50) {
        short4v o;
        #pragma unroll
        for (int u = 0; u < 4; u++) o[u] = f2bf(a[u] * inv);
        *(short4v*)((short*)hbar + (long)v * LDA + lane * 4) = o;
    }
}

// ---------------------------------------------------------------------------
// GNN fused softmax+agg: c[v] = elu(softmax-weighted sum of hvp[src]).
// ---------------------------------------------------------------------------
__global__ __launch_bounds__(256)
void gnn_fused_agg_kernel(const __hip_bfloat16* __restrict__ X,
                          const int* __restrict__ src,
                          const int* __restrict__ rp, const int* __restrict__ perm,
                          const float* __restrict__ s1, const float* __restrict__ s2,
                          const float* __restrict__ bias,
                          __hip_bfloat16* __restrict__ out)
{
    const int tid = threadIdx.x;
    const int w = tid >> 6, lane = tid & 63;
    const int vlane = (lane < 50) ? lane : 0;
    int v = blockIdx.x * 4 + w;
    if (v >= V_N) return;
    int b = rp[v], en = rp[v + 1];
    float s1v = s1[v] + bias[0];
    f32x4 a = {};
    float m = -INFINITY, s = 0.f;
    for (int cb0 = b; cb0 < en; cb0 += 64) {
        int i = cb0 + lane;
        int sE = 0;
        float l = -INFINITY;
        if (i < en) { int e = perm[i]; sE = src[e]; l = lrelu_f(s1v + s2[sE]); }
        float lmax = l;
        for (int off = 32; off > 0; off >>= 1) lmax = fmaxf(lmax, __shfl_xor(lmax, off, 64));
        float m_new = fmaxf(m, lmax);
        float scale = expf(m - m_new);
        s *= scale; a *= scale;
        float wgt = (i < en) ? expf(l - m_new) : 0.f;
        float wsum = wgt;
        for (int off = 32; off > 0; off >>= 1) wsum += __shfl_xor(wsum, off, 64);
        s += wsum;
        int cnt = min(64, en - cb0);
        for (int t = 0; t < cnt; t++) {
            int sT = __shfl(sE, t, 64);
            float wT = __shfl(wgt, t, 64);
            short4v pv = *(const short4v*)((const short*)X + (long)sT * LDA + vlane * 4);
            #pragma unroll
            for (int u = 0; u < 4; u++)
                a[u] += wT * bfbits2f(pv[u]);
        }
        m = m_new;
    }
    float inv = (s > 0.f) ? 1.f / s : 0.f;
    if (lane < 50) {
        short4v o;
        #pragma unroll
        for (int u = 0; u < 4; u++) o[u] = f2bf(elu_f(a[u] * inv));
        *(short4v*)((short*)out + (long)v * LDA + lane * 4) = o;
    }
}

// ---------------------------------------------------------------------------
// readout
// ---------------------------------------------------------------------------
__global__ __launch_bounds__(256)
void mask_kernel(const float* __restrict__ nfeat, float* __restrict__ mask)
{
    int v = blockIdx.x * blockDim.x + threadIdx.x;
    if (v >= V_N) return;
    const float* row = nfeat + (long)v * NFEAT;
    float s = row[NFEAT - 4] + row[NFEAT - 3] + row[NFEAT - 2] + row[NFEAT - 1];
    float m = s * (1.f - row[0]);
    mask[v] = 1.f / m - 1.f;
}

__global__ __launch_bounds__(256)
void readout_kernel(const __hip_bfloat16* __restrict__ nf, const float* __restrict__ predW,
                    const float* __restrict__ predb, const float* __restrict__ mask,
                    const int* __restrict__ gid, float* __restrict__ out_atom,
                    float* __restrict__ gsum)
{
    int gtid = blockIdx.x * blockDim.x + threadIdx.x;
    int v = gtid >> 6, lane = gtid & 63;
    if (v >= V_N) return;
    int vlane = (lane < 50) ? lane : 0;
    short4v pv = *(const short4v*)((const short*)nf + (long)v * LDA + vlane * 4);
    f32x4 wv = *(const f32x4*)(predW + vlane * 4);
    float acc = 0.f;
    #pragma unroll
    for (int u = 0; u < 4; u++) acc += bfbits2f(pv[u]) * wv[u];
    if (lane >= 50) acc = 0.f;
    for (int off = 32; off > 0; off >>= 1) acc += __shfl_down(acc, off, 64);
    if (lane == 0) {
        float p = acc + predb[0] + mask[v];
        out_atom[v] = p;
        atomicAdd(&gsum[gid[v]], exp10f(-p));
    }
}

__global__ __launch_bounds__(256)
void graph_out_kernel(const float* __restrict__ gsum, float* __restrict__ out_g)
{
    int g = blockIdx.x * blockDim.x + threadIdx.x;
    if (g >= NG_N) return;
    out_g[g] = -log10f(gsum[g]);
}

// ---------------------------------------------------------------------------
extern "C" void kernel_launch(void* const* d_in, const int* in_sizes, int n_in,
                              void* d_out, int out_size, void* d_ws, size_t ws_size,
                              hipStream_t stream)
{
    const float* node_feats = (const float*)d_in[0];
    const float* edge_feats = (const float*)d_in[1];
    const float* pn_W  = (const float*)d_in[2];
    const float* pn_b  = (const float*)d_in[3];
    const float* pe1_W = (const float*)d_in[4];
    const float* pe1_b = (const float*)d_in[5];
    const float* pe2_W = (const float*)d_in[6];
    const float* pe2_b = (const float*)d_in[7];
    const float* et_W  = (const float*)d_in[8];
    const float* et_b  = (const float*)d_in[9];
    const float* gru0_Wih = (const float*)d_in[10];
    const float* gru0_Whh = (const float*)d_in[11];
    const float* gru0_bih = (const float*)d_in[12];
    const float* gru0_bhh = (const float*)d_in[13];
    const float* gnn_pe_W = (const float*)d_in[14];
    const float* gnn_pe_b = (const float*)d_in[15];
    const float* gnn_pn_W = (const float*)d_in[16];
    const float* gnn_pn_b = (const float*)d_in[17];
    const float* gnn_gru_Wih = (const float*)d_in[18];
    const float* gnn_gru_Whh = (const float*)d_in[19];
    const float* gnn_gru_bih = (const float*)d_in[20];
    const float* gnn_gru_bhh = (const float*)d_in[21];
    const float* pred_W = (const float*)d_in[22];
    const float* pred_b = (const float*)d_in[23];
    const int* src = (const int*)d_in[24];
    const int* dst = (const int*)d_in[25];
    const int* gid = (const int*)d_in[26];

    float* out_g = (float*)d_out;
    float* out_atom = out_g + NG_N;

    char* base = (char*)d_ws;
    size_t off = 0;
    auto take = [&](size_t bytes) -> void* {
        void* p = base + off;
        off += (bytes + 255) & ~(size_t)255;
        return p;
    };
    const size_t VP = (size_t)V_N * LDA;
    const size_t WPL = (size_t)14 * 14 * 1536;   // = 301056, same as before
    float* mask   = (float*)take((size_t)V_N * 4);
    float* logits = (float*)take((size_t)E_N * 4);
    float* s1     = (float*)take((size_t)V_N * 4);
    float* s2     = (float*)take((size_t)V_N * 4);
    float* gsum   = (float*)take((size_t)NG_N * 4);
    __hip_bfloat16* c    = (__hip_bfloat16*)take(VP * 2);
    __hip_bfloat16* hv   = (__hip_bfloat16*)take(VP * 2);
    __hip_bfloat16* nf_a = (__hip_bfloat16*)take(VP * 2);
    __hip_bfloat16* nf_b = (__hip_bfloat16*)take(VP * 2);
    short* WpGru = (short*)take(3 * WPL * 2);
    short* Wp_pn0 = (short*)take((size_t)256 * 96 * 2);
    short* Wp_pe1 = (short*)take((size_t)256 * 96 * 2);
    short* Wp_et  = (short*)take((size_t)7 * 7 * 1024 * 2);
    short* Wp_pn1 = (short*)take((size_t)7 * 7 * 1024 * 2);
    short* Wp_pn2 = (short*)take((size_t)7 * 7 * 1024 * 2);
    int* deg  = (int*)take((size_t)V_N * 4);
    int* cnt  = (int*)take((size_t)V_N * 4);
    int* rp   = (int*)take((size_t)(V_N + 1) * 4);
    int* perm = (int*)take((size_t)E_N * 4);
    int* bsum = (int*)take((size_t)512 * 4);
    __hip_bfloat16* P    = nf_a;  // alias: nf_a written only at GRU0
    __hip_bfloat16* hbar = nf_b;  // alias: nf_b first written as layer-0 GRU output
    __hip_bfloat16* hvp  = hv;    // alias: hv dead after GRU0

    if (off > ws_size) {
        fill_kernel<<<cdiv(out_size, 256), 256, 0, stream>>>((float*)d_out, -12345.f, out_size);
        return;
    }

    const int BLK = 256;
    const int nScanBlocks = cdiv(V_N, 256);
    const dim3 gOld(4, cdiv(V_N, 64));
    const int gAgg = cdiv(V_N, 4);

    // zero only the pad columns of the 4 contiguous node matrices
    pad_zero_kernel<<<cdiv(4 * V_N, BLK), BLK, 0, stream>>>((short*)c, VP);

    // ---- weight prep ----
    gru_wprep_kernel<<<cdiv(14 * 14 * 1536, 256), BLK, 0, stream>>>(gru0_Wih, gru0_Whh, WpGru);
    for (int l = 0; l < L_N; l++)
        gru_wprep_kernel<<<cdiv(14 * 14 * 1536, 256), BLK, 0, stream>>>(
            gnn_gru_Wih + (size_t)l * G_DIM * 3 * G_DIM,
            gnn_gru_Whh + (size_t)l * G_DIM * 3 * G_DIM,
            WpGru + (size_t)(l + 1) * WPL);
    wprep_kernel<<<cdiv(256 * 96, 256), BLK, 0, stream>>>(pn_W, Wp_pn0, NFEAT, 96);
    wprep_kernel<<<cdiv(256 * 96, 256), BLK, 0, stream>>>(pe1_W, Wp_pe1, NFEAT, 96);
    wprep_tiled_kernel<<<cdiv(7 * 7 * 1024, 256), BLK, 0, stream>>>(et_W, Wp_et);
    wprep_tiled_kernel<<<cdiv(7 * 7 * 1024, 256), BLK, 0, stream>>>(gnn_pn_W, Wp_pn1);
    wprep_tiled_kernel<<<cdiv(7 * 7 * 1024, 256), BLK, 0, stream>>>(
        gnn_pn_W + (size_t)G_DIM * G_DIM, Wp_pn2);

    mask_kernel<<<cdiv(V_N, BLK), BLK, 0, stream>>>(node_feats, mask);

    // ---- CSR build (by dst) ----
    fill_int_kernel<<<cdiv(V_N, BLK), BLK, 0, stream>>>(deg, 0, V_N);
    hist_kernel<<<cdiv(E_N, BLK), BLK, 0, stream>>>(dst, deg);
    scan1_kernel<<<nScanBlocks, BLK, 0, stream>>>(deg, rp, bsum);
    scan2_kernel<<<1, 1, 0, stream>>>(bsum, rp, nScanBlocks);
    scan3_kernel<<<nScanBlocks, BLK, 0, stream>>>(rp, bsum);
    fill_int_kernel<<<cdiv(V_N, BLK), BLK, 0, stream>>>(cnt, 0, V_N);
    csr_fill_kernel<<<cdiv(E_N, BLK), BLK, 0, stream>>>(dst, rp, cnt, perm);

    // ---- GetContext ----
    gemm_f32a_dual_kernel<<<gOld, BLK, 0, stream>>>(
        node_feats, Wp_pn0, pn_b, Wp_pe1, pe1_b, hv, P);
    node_dot2_kernel<<<gAgg, BLK, 0, stream>>>(hv, pe2_W, nullptr, s1, nullptr);
    ctx_logits_kernel<<<cdiv(E_N, 8), BLK, 0, stream>>>(
        P, edge_feats, src, dst, s1, pe1_W, pe2_W, pe2_b, logits);
    ctx_fused_agg_kernel<<<gAgg, BLK, 0, stream>>>(
        P, edge_feats, src, rp, perm, logits, pe1_W, hbar);
    gemm_bf16a_kernel<3><<<NSWZ, BLK, 0, stream>>>(hbar, Wp_et, et_b, c);
    gru_mfma_kernel<<<NSWZG, BLK, 0, stream>>>(c, hv, WpGru, gru0_bih, gru0_bhh, nf_a);

    // ---- GNN layers ----
    __hip_bfloat16* cur = nf_a;
    __hip_bfloat16* nxt = nf_b;
    for (int l = 0; l < L_N; l++) {
        const float* pe_W = gnn_pe_W + (size_t)l * 2 * G_DIM;
        const float* pe_b = gnn_pe_b + l;
        const float* pnB  = gnn_pn_b + (size_t)l * G_DIM;
        const float* bih  = gnn_gru_bih + (size_t)l * 3 * G_DIM;
        const float* bhh  = gnn_gru_bhh + (size_t)l * 3 * G_DIM;
        const short* WpPn = (l == 0) ? Wp_pn1 : Wp_pn2;

        node_dot2_kernel<<<gAgg, BLK, 0, stream>>>(cur, pe_W, pe_W + G_DIM, s1, s2);
        gemm_bf16a_kernel<1><<<NSWZ, BLK, 0, stream>>>(cur, WpPn, pnB, hvp);
        gnn_fused_agg_kernel<<<gAgg, BLK, 0, stream>>>(
            hvp, src, rp, perm, s1, s2, pe_b, c);
        gru_mfma_kernel<<<NSWZG, BLK, 0, stream>>>(
            c, cur, WpGru + (size_t)(l + 1) * WPL, bih, bhh, nxt);

        __hip_bfloat16* tmp = cur; cur = nxt; nxt = tmp;
    }

    // ---- readout ----
    fill_kernel<<<cdiv(NG_N, BLK), BLK, 0, stream>>>(gsum, 0.f, NG_N);
    readout_kernel<<<cdiv(V_N * 64, BLK), BLK, 0, stream>>>(
        cur, pred_W, pred_b, mask, gid, out_atom, gsum);
    graph_out_kernel<<<cdiv(NG_N, BLK), BLK, 0, stream>>>(gsum, out_g);
}